// Round 5
// baseline (4939.335 us; speedup 1.0000x reference)
//
#include <hip/hip_runtime.h>
#include <hip/hip_bf16.h>
#include <string.h>

#define TT 128   // time steps
#define BB 1024  // batch
#define DD 256   // deter dim
#define SS 32    // stoch dim
#define HHID 256 // hidden
#define NC 1280  // combined phase-A cols: 256 P1 | 256 Q1 | 768 gh
#define RR 4     // batch rows per block (4 -> 256 blocks -> 1 block/CU)

typedef __attribute__((ext_vector_type(8))) short bf16x8;
typedef __attribute__((ext_vector_type(4))) float f32x4;

__device__ __forceinline__ float eluf(float x)   { return x > 0.f ? x : __expf(x) - 1.f; }
__device__ __forceinline__ float sigf(float x)   { return 1.f / (1.f + __expf(-x)); }
__device__ __forceinline__ float tanhf_(float x) { float e = __expf(2.f * x); return (e - 1.f) / (e + 1.f); }
__device__ __forceinline__ float clip75(float x) { return fminf(fmaxf(x, -7.f), 5.f); }

// barrier that only drains LDS (lgkmcnt): global out-stores (never re-read)
// stay in flight across the barrier. All global LOADS have register consumers,
// so the compiler inserts their vmcnt waits at the use sites.
__device__ __forceinline__ void bar_lds() {
    asm volatile("s_waitcnt lgkmcnt(0)\n\ts_barrier" ::: "memory");
}

// unpack a uint holding two bf16 (low ushort = first element) to float2
__device__ __forceinline__ float2 bf2f2(unsigned int u) {
    union { unsigned int i; float f; } a, b;
    a.i = (u & 0xffffu) << 16;
    b.i = u & 0xffff0000u;
    return make_float2(a.f, b.f);
}

// ---------------- weight transpose (for obs encoder): dst[k*dld + dcoff + n] = src[n*sld + soff + k] ----
__global__ void transpose_k(const float* __restrict__ src, float* __restrict__ dst,
                            int N, int K, int soff, int sld, int dld, int dcoff)
{
    int idx = blockIdx.x * 256 + threadIdx.x;
    if (idx >= N * K) return;
    int k = idx / N, n = idx - k * N;
    dst[k * dld + dcoff + n] = src[n * sld + soff + k];
}

// ---------------- prep: Wcomb -> MFMA B-fragment-major bf16 ----------------
// dst[((nt*8+ks)*64+lane)*8 + j] = Wcomb[nt*16 + (lane&15)][ks*32 + (lane>>4)*8 + j]
// Wcomb rows: [0,256)=W_p1, [256,512)=W_q1 h-part, [512,1280)=W_hh
__global__ void prep_wcomb(const float* __restrict__ Wp1, const float* __restrict__ Wq1,
                           const float* __restrict__ Whh, __hip_bfloat16* __restrict__ dst)
{
    int idx = blockIdx.x * 256 + threadIdx.x;
    if (idx >= NC * DD) return;
    int j = idx & 7, lane = (idx >> 3) & 63, ks = (idx >> 9) & 7, nt = idx >> 12;
    int n = nt * 16 + (lane & 15);
    int k = ks * 32 + (lane >> 4) * 8 + j;
    float v;
    if (n < 256)      v = Wp1[n * 256 + k];
    else if (n < 512) v = Wq1[(n - 256) * 512 + k];
    else              v = Whh[(n - 512) * 256 + k];
    dst[idx] = __float2bfloat16(v);
}

// ---------------- prep: W2 [64][256] -> uint4-packed bf16 ----------------
// uint4 at (kg*64 + l) holds k = kg*8 .. kg*8+7 for stat l.
// flat bf16 idx = kg*512 + l*8 + q*2 + par  ->  W[l][kg*8 + q*2 + par]
__global__ void prep_w2(const float* __restrict__ W, __hip_bfloat16* __restrict__ dst)
{
    int idx = blockIdx.x * 256 + threadIdx.x;
    if (idx >= 64 * 256) return;
    int par = idx & 1, q = (idx >> 1) & 3, l = (idx >> 3) & 63, kg = idx >> 9;
    dst[idx] = __float2bfloat16(W[l * 256 + kg * 8 + q * 2 + par]);
}

// ---------------- prep: W_ih [768][40] -> uint4-packed [kp][j][gate(+pad)] bf16 ----------------
// uint4 at (kp*256 + j): .x = gate r pair, .y = gate z pair, .z = gate n pair, .w = 0
// flat bf16 idx = kp*2048 + j*8 + g*2 + par -> W[(g*256+j)*40 + kp*2 + par]
__global__ void prep_wih(const float* __restrict__ W, __hip_bfloat16* __restrict__ dst)
{
    int idx = blockIdx.x * 256 + threadIdx.x;
    if (idx >= 20 * 256 * 8) return;
    int par = idx & 1, g = (idx >> 1) & 3, j = (idx >> 3) & 255, kp = idx >> 11;
    float v = 0.f;
    if (g < 3) v = W[(g * 256 + j) * 40 + kp * 2 + par];
    dst[idx] = __float2bfloat16(v);
}

// ---------------- fused obs encoder -> Qpre[t][b][:] = emb @ Wq1_e^T + b_q1 (fp32) ----------------
__global__ void __launch_bounds__(256) obs_enc_k(
    const float* __restrict__ obs, const float* __restrict__ We1t,
    const float* __restrict__ be1, const float* __restrict__ We2t,
    const float* __restrict__ be2, const float* __restrict__ Wq1et,
    const float* __restrict__ bq1, float* __restrict__ Qpre)
{
    __shared__ float buf0[32 * 256];
    __shared__ float buf1[32 * 256];
    const int tid = threadIdx.x;
    const int r0 = blockIdx.x * 32;
    const int tx = tid & 31, ty = tid >> 5;
    const int colb = tx * 8;
    float acc[4][8];

#pragma unroll
    for (int i = 0; i < 4; ++i)
#pragma unroll
        for (int j = 0; j < 8; ++j) acc[i][j] = 0.f;
#pragma unroll 4
    for (int k = 0; k < 64; ++k) {
        float4 w0 = *(const float4*)&We1t[k * 256 + colb];
        float4 w1 = *(const float4*)&We1t[k * 256 + colb + 4];
#pragma unroll
        for (int i = 0; i < 4; ++i) {
            float a = obs[(r0 + ty * 4 + i) * 64 + k];
            acc[i][0] += a * w0.x; acc[i][1] += a * w0.y; acc[i][2] += a * w0.z; acc[i][3] += a * w0.w;
            acc[i][4] += a * w1.x; acc[i][5] += a * w1.y; acc[i][6] += a * w1.z; acc[i][7] += a * w1.w;
        }
    }
#pragma unroll
    for (int i = 0; i < 4; ++i)
#pragma unroll
        for (int j = 0; j < 8; ++j)
            buf0[(ty * 4 + i) * 256 + colb + j] = eluf(acc[i][j] + be1[colb + j]);
    __syncthreads();

#pragma unroll
    for (int i = 0; i < 4; ++i)
#pragma unroll
        for (int j = 0; j < 8; ++j) acc[i][j] = 0.f;
#pragma unroll 4
    for (int k = 0; k < 256; ++k) {
        float4 w0 = *(const float4*)&We2t[k * 256 + colb];
        float4 w1 = *(const float4*)&We2t[k * 256 + colb + 4];
#pragma unroll
        for (int i = 0; i < 4; ++i) {
            float a = buf0[(ty * 4 + i) * 256 + k];
            acc[i][0] += a * w0.x; acc[i][1] += a * w0.y; acc[i][2] += a * w0.z; acc[i][3] += a * w0.w;
            acc[i][4] += a * w1.x; acc[i][5] += a * w1.y; acc[i][6] += a * w1.z; acc[i][7] += a * w1.w;
        }
    }
#pragma unroll
    for (int i = 0; i < 4; ++i)
#pragma unroll
        for (int j = 0; j < 8; ++j)
            buf1[(ty * 4 + i) * 256 + colb + j] = eluf(acc[i][j] + be2[colb + j]);
    __syncthreads();

#pragma unroll
    for (int i = 0; i < 4; ++i)
#pragma unroll
        for (int j = 0; j < 8; ++j) acc[i][j] = 0.f;
#pragma unroll 4
    for (int k = 0; k < 256; ++k) {
        float4 w0 = *(const float4*)&Wq1et[k * 256 + colb];
        float4 w1 = *(const float4*)&Wq1et[k * 256 + colb + 4];
#pragma unroll
        for (int i = 0; i < 4; ++i) {
            float a = buf1[(ty * 4 + i) * 256 + k];
            acc[i][0] += a * w0.x; acc[i][1] += a * w0.y; acc[i][2] += a * w0.z; acc[i][3] += a * w0.w;
            acc[i][4] += a * w1.x; acc[i][5] += a * w1.y; acc[i][6] += a * w1.z; acc[i][7] += a * w1.w;
        }
    }
#pragma unroll
    for (int i = 0; i < 4; ++i) {
        int r = r0 + ty * 4 + i;
        int b = r >> 7, t = r & (TT - 1);   // row = b*T + t
        float* dst = Qpre + ((size_t)t * BB + b) * HHID + colb;
#pragma unroll
        for (int j = 0; j < 8; ++j)
            dst[j] = acc[i][j] + bq1[colb + j];
    }
}

// ---------------- main sequential kernel: block = RR=4 batch rows, 1024 threads (16 waves) ----------------
// Round-4 winning structure scaled to 4 waves/SIMD. Per-wave Phase A: 5 CONTIGUOUS
// tiles, identical bbuf[2][8] register double-buffer, unroll 2 (never full unroll:
// rounds 1/3 showed full unroll -> VGPR blowup -> L2 thrash). Plain launch_bounds
// (compiler caps VGPR at 128 to fit the 16-wave block; round-4 usage was 100).
__global__ void __launch_bounds__(1024) rssm_seq(
    const float* __restrict__ act, const float* __restrict__ noise,
    const __hip_bfloat16* __restrict__ Wfrag, const float* __restrict__ b_p1,
    const float* __restrict__ b_hh, const float* __restrict__ Qpre,
    const uint4* __restrict__ Wp2q, const float* __restrict__ b_p2,
    const uint4* __restrict__ Wq2q, const float* __restrict__ b_q2,
    const uint4* __restrict__ Wihq, const float* __restrict__ b_ih,
    float* __restrict__ out)
{
    __shared__ float CA[RR][NC];                // P1 | Q1 | gh for our RR rows
    __shared__ float h32[RR][DD];
    __shared__ __hip_bfloat16 hbf[16][264];     // MFMA A operand, rows RR..15 zero, +8 pad
    __shared__ float zl[RR][SS];
    __shared__ float actl[RR][8];
    __shared__ float qbuf[2][RR][HHID];         // Qpre staging, double-buffered by t

    const int tid = threadIdx.x;
    const int wave = tid >> 6, lane = tid & 63;
    const int blk = blockIdx.x;

    for (int i = tid; i < 16 * 264; i += 1024) ((unsigned short*)hbf)[i] = 0;
    for (int i = tid; i < RR * DD; i += 1024) ((float*)h32)[i] = 0.f;
    if (tid < 512) {   // prologue: stage Qpre for t = 0
        const int qi = tid * 2, qreg = qi >> 8, qcol = qi & 255;
        *(float2*)&qbuf[0][qreg][qcol] =
            *(const float2*)&Qpre[((size_t)0 * BB + blk * RR + qreg) * HHID + qcol];
    }
    __syncthreads();

    const int am = lane & 15, aq = lane >> 4;
    // wave handles CONTIGUOUS N-tiles nt = wave*5 + i, i = 0..4
    const bf16x8* wp = (const bf16x8*)Wfrag + (size_t)wave * 40 * 64 + lane;

    for (int t = 0; t < TT; ++t) {
        // ---- early prefetches (register consumers far downstream) ----
        if (tid < RR * 8) {
            int row = tid >> 3, c = tid & 7;
            actl[row][c] = act[((size_t)(blk * RR + row) * TT + t) * 8 + c];
        }
        float nval = 0.f;
        if (wave >= 4 && wave < 8 && lane < 32)
            nval = noise[((size_t)t * BB + blk * RR + (wave & 3)) * SS + lane];
        float2 qv = make_float2(0.f, 0.f);
        if (t + 1 < TT && tid < 512) {
            const int qi = tid * 2, qreg = qi >> 8, qcol = qi & 255;
            qv = *(const float2*)&Qpre[((size_t)(t + 1) * BB + blk * RR + qreg) * HHID + qcol];
        }

        // ======== Phase A: CA[RR][1280] = epilogue(h @ Wcomb^T) via MFMA ========
        bf16x8 afr[8];
#pragma unroll
        for (int ks = 0; ks < 8; ++ks)
            afr[ks] = *(const bf16x8*)&hbf[am][ks * 32 + aq * 8];

        bf16x8 bbuf[2][8];
#pragma unroll
        for (int ks = 0; ks < 8; ++ks) bbuf[0][ks] = wp[(size_t)ks * 64];
#pragma unroll 2
        for (int i = 0; i < 5; ++i) {
            const int cb = i & 1;
            if (i < 4) {
#pragma unroll
                for (int ks = 0; ks < 8; ++ks)
                    bbuf[cb ^ 1][ks] = wp[(size_t)((i + 1) * 8 + ks) * 64];
            }
            f32x4 acc = {0.f, 0.f, 0.f, 0.f};
#pragma unroll
            for (int ks = 0; ks < 8; ++ks)
                acc = __builtin_amdgcn_mfma_f32_16x16x32_bf16(afr[ks], bbuf[cb][ks], acc, 0, 0, 0);
            const int nt = wave * 5 + i;
            if (lane < 16) {   // quad 0 holds rows 0..3 (row = reg, col = nt*16+lane)
                const int col = nt * 16 + lane;
                if (nt < 16) {
#pragma unroll
                    for (int reg = 0; reg < RR; ++reg)
                        CA[reg][col] = eluf(acc[reg] + b_p1[col]);
                } else if (nt < 32) {
#pragma unroll
                    for (int reg = 0; reg < RR; ++reg)
                        CA[reg][col] = eluf(acc[reg] + qbuf[t & 1][reg][col - 256]);
                } else {
#pragma unroll
                    for (int reg = 0; reg < RR; ++reg)
                        CA[reg][col] = acc[reg] + b_hh[col - 512];
                }
            }
        }
        bar_lds();

        // ======== Phase B1: stats + z. waves 0-7: wave = (isq<<2) | row ========
        if (wave < 8) {
            const int row = wave & 3, isq = wave >> 2;
            const float* car = CA[row] + (isq ? 256 : 0);
            const uint4* W2 = isq ? Wq2q : Wp2q;
            float dA = isq ? b_q2[lane] : b_p2[lane];
            float dB = 0.f;
#pragma unroll 4
            for (int kg = 0; kg < 32; ++kg) {
                uint4 wv = W2[kg * 64 + lane];
                float4 c0 = *(const float4*)&car[kg * 8];
                float4 c1 = *(const float4*)&car[kg * 8 + 4];
                float2 w;
                w = bf2f2(wv.x); dA += c0.x * w.x + c0.y * w.y;
                w = bf2f2(wv.y); dB += c0.z * w.x + c0.w * w.y;
                w = bf2f2(wv.z); dA += c1.x * w.x + c1.y * w.y;
                w = bf2f2(wv.w); dB += c1.z * w.x + c1.w * w.y;
            }
            float d = dA + dB;
            const int r = blk * RR + row;
            float* orow = out + ((size_t)r * TT + t) * 416;
            float v = (lane < 32) ? d : __expf(clip75(d));
            if (!isq) {
                orow[288 + lane] = v;                        // prior mean | prior std
            } else {
                orow[352 + lane] = v;                        // post mean | post std
                float qs_hi = __shfl(v, lane + 32, 64);
                if (lane < 32) {
                    float z = v + qs_hi * nval;
                    zl[row][lane] = z;
                    orow[256 + lane] = z;
                }
            }
        }
        // stage Qpre for t+1 (loads issued at step top, hidden under the B1 dot)
        if (t + 1 < TT && tid < 512) {
            const int qi = tid * 2;
            *(float2*)&qbuf[(t + 1) & 1][qi >> 8][qi & 255] = qv;
        }
        bar_lds();

        // ======== Phase B2: GRU. thread = (row r = tid>>8, column j = tid&255) ========
        {
            const int j = tid & 255, r = tid >> 8;
            float g0 = b_ih[j], g1 = b_ih[256 + j], g2 = b_ih[512 + j];
#pragma unroll 4
            for (int kp = 0; kp < 20; ++kp) {
                uint4 w4 = Wihq[kp * 256 + j];
                float2 wr = bf2f2(w4.x), wz = bf2f2(w4.y), wn = bf2f2(w4.z);
                float2 a2 = (kp < 16) ? *(const float2*)&zl[r][kp * 2]
                                      : *(const float2*)&actl[r][(kp - 16) * 2];
                g0 += a2.x * wr.x + a2.y * wr.y;
                g1 += a2.x * wz.x + a2.y * wz.y;
                g2 += a2.x * wn.x + a2.y * wn.y;
            }
            float rg = sigf(g0 + CA[r][512 + j]);
            float ug = sigf(g1 + CA[r][768 + j]);
            float ng = tanhf_(g2 + rg * CA[r][1024 + j]);
            float hold = h32[r][j];
            float hn = (1.f - ug) * ng + ug * hold;
            out[((size_t)(blk * RR + r) * TT + t) * 416 + j] = hold;  // h at step entry
            h32[r][j] = hn;
            hbf[r][j] = __float2bfloat16(hn);
        }
        bar_lds();   // hbf/h32/CA/qbuf stable before next step's Phase A
    }
}

extern "C" void kernel_launch(void* const* d_in, const int* in_sizes, int n_in,
                              void* d_out, int out_size, void* d_ws, size_t ws_size,
                              hipStream_t stream)
{
    const float* obs   = (const float*)d_in[0];
    const float* act   = (const float*)d_in[1];
    const float* noise = (const float*)d_in[2];
    const float* W_e1  = (const float*)d_in[3];
    const float* b_e1  = (const float*)d_in[4];
    const float* W_e2  = (const float*)d_in[5];
    const float* b_e2  = (const float*)d_in[6];
    const float* W_ih  = (const float*)d_in[7];
    const float* W_hh  = (const float*)d_in[8];
    const float* b_ih  = (const float*)d_in[9];
    const float* b_hh  = (const float*)d_in[10];
    const float* W_p1  = (const float*)d_in[11];
    const float* b_p1  = (const float*)d_in[12];
    const float* W_p2  = (const float*)d_in[13];
    const float* b_p2  = (const float*)d_in[14];
    const float* W_q1  = (const float*)d_in[15];
    const float* b_q1  = (const float*)d_in[16];
    const float* W_q2  = (const float*)d_in[17];
    const float* b_q2  = (const float*)d_in[18];
    float* outp = (float*)d_out;

    // workspace layout
    const size_t qpre_elems = (size_t)TT * BB * HHID;           // 33,554,432 f32
    float* Qpre  = (float*)d_ws;
    float* We1t  = Qpre + qpre_elems;       // 64*256
    float* We2t  = We1t + 64 * 256;         // 256*256
    float* Wq1et = We2t + 256 * 256;        // 256*256
    __hip_bfloat16* Wfrag = (__hip_bfloat16*)(Wq1et + 256 * 256);  // 1280*256
    __hip_bfloat16* Wp2b  = Wfrag + NC * DD;                       // 16384 (uint4-packed)
    __hip_bfloat16* Wq2b  = Wp2b + 64 * 256;                       // 16384 (uint4-packed)
    __hip_bfloat16* Wihb  = Wq2b + 64 * 256;                       // 40960 (uint4-packed, padded)
    size_t total_bytes = (char*)(Wihb + 20 * 256 * 8) - (char*)d_ws;
    if (ws_size < total_bytes) return;

    auto tl = [&](const float* s, float* d, int N, int K, int soff, int sld, int dld, int dcoff) {
        int tot = N * K;
        transpose_k<<<(tot + 255) / 256, 256, 0, stream>>>(s, d, N, K, soff, sld, dld, dcoff);
    };
    tl(W_e1, We1t, 256, 64, 0, 64, 256, 0);
    tl(W_e2, We2t, 256, 256, 0, 256, 256, 0);
    tl(W_q1, Wq1et, 256, 256, 256, 512, 256, 0);   // emb-part of W_q1

    prep_wcomb<<<(NC * DD + 255) / 256, 256, 0, stream>>>(W_p1, W_q1, W_hh, Wfrag);
    prep_w2<<<(64 * 256 + 255) / 256, 256, 0, stream>>>(W_p2, Wp2b);
    prep_w2<<<(64 * 256 + 255) / 256, 256, 0, stream>>>(W_q2, Wq2b);
    prep_wih<<<(20 * 256 * 8 + 255) / 256, 256, 0, stream>>>(W_ih, Wihb);

    obs_enc_k<<<dim3((BB * TT) / 32), dim3(256), 0, stream>>>(
        obs, We1t, b_e1, We2t, b_e2, Wq1et, b_q1, Qpre);

    rssm_seq<<<dim3(BB / RR), dim3(1024), 0, stream>>>(
        act, noise, Wfrag, b_p1, b_hh, Qpre,
        (const uint4*)Wp2b, b_p2,
        (const uint4*)Wq2b, b_q2,
        (const uint4*)Wihb, b_ih, outp);
}

// Round 6
// 1878.655 us; speedup vs baseline: 2.6292x; 2.6292x over previous
//
#include <hip/hip_runtime.h>
#include <hip/hip_bf16.h>
#include <string.h>

#define TT 128   // time steps
#define BB 1024  // batch
#define DD 256   // deter dim
#define SS 32    // stoch dim
#define HHID 256 // hidden
#define NC 1280  // combined phase-A cols: 256 P1 | 256 Q1 | 768 gh
#define RR 4     // batch rows per block (4 -> 256 blocks -> 1 block/CU)

typedef __attribute__((ext_vector_type(8))) short bf16x8;
typedef __attribute__((ext_vector_type(4))) float f32x4;

__device__ __forceinline__ float eluf(float x)   { return x > 0.f ? x : __expf(x) - 1.f; }
__device__ __forceinline__ float sigf(float x)   { return 1.f / (1.f + __expf(-x)); }
__device__ __forceinline__ float tanhf_(float x) { float e = __expf(2.f * x); return (e - 1.f) / (e + 1.f); }
__device__ __forceinline__ float clip75(float x) { return fminf(fmaxf(x, -7.f), 5.f); }

// barrier that only drains LDS (lgkmcnt): global out-stores (never re-read)
// stay in flight across the barrier. All global LOADS have register consumers,
// so the compiler inserts their vmcnt waits at the use sites.
__device__ __forceinline__ void bar_lds() {
    asm volatile("s_waitcnt lgkmcnt(0)\n\ts_barrier" ::: "memory");
}

// unpack a uint holding two bf16 (low ushort = first element) to float2
__device__ __forceinline__ float2 bf2f2(unsigned int u) {
    union { unsigned int i; float f; } a, b;
    a.i = (u & 0xffffu) << 16;
    b.i = u & 0xffff0000u;
    return make_float2(a.f, b.f);
}

__device__ __forceinline__ bf16x8 pack8(const float* p) {
    bf16x8 r;
#pragma unroll
    for (int j = 0; j < 8; ++j) {
        __hip_bfloat16 h = __float2bfloat16(p[j]);
        r[j] = *reinterpret_cast<short*>(&h);
    }
    return r;
}

// ---------------- prep: Wcomb -> MFMA B-fragment-major bf16 ----------------
// dst[((nt*8+ks)*64+lane)*8 + j] = Wcomb[nt*16 + (lane&15)][ks*32 + (lane>>4)*8 + j]
// Wcomb rows: [0,256)=W_p1, [256,512)=W_q1 h-part, [512,1280)=W_hh
__global__ void prep_wcomb(const float* __restrict__ Wp1, const float* __restrict__ Wq1,
                           const float* __restrict__ Whh, __hip_bfloat16* __restrict__ dst)
{
    int idx = blockIdx.x * 256 + threadIdx.x;
    if (idx >= NC * DD) return;
    int j = idx & 7, lane = (idx >> 3) & 63, ks = (idx >> 9) & 7, nt = idx >> 12;
    int n = nt * 16 + (lane & 15);
    int k = ks * 32 + (lane >> 4) * 8 + j;
    float v;
    if (n < 256)      v = Wp1[n * 256 + k];
    else if (n < 512) v = Wq1[(n - 256) * 512 + k];
    else              v = Whh[(n - 512) * 256 + k];
    dst[idx] = __float2bfloat16(v);
}

// ---------------- generic prep: [N][K] (strided, offset) -> MFMA B-fragment-major bf16 ----
// dst[((nt*(K/32)+ks)*64+lane)*8 + j] = src[(nt*16+(lane&15))*sld + soff + ks*32+(lane>>4)*8+j]
__global__ void prep_bfrag(const float* __restrict__ src, __hip_bfloat16* __restrict__ dst,
                           int N, int K, int soff, int sld)
{
    int idx = blockIdx.x * 256 + threadIdx.x;
    if (idx >= N * K) return;
    int j = idx & 7, lane = (idx >> 3) & 63;
    int t = idx >> 9;
    int ksn = K >> 5;
    int ks = t % ksn, nt = t / ksn;
    int n = nt * 16 + (lane & 15);
    int k = ks * 32 + (lane >> 4) * 8 + j;
    dst[idx] = __float2bfloat16(src[n * sld + soff + k]);
}

// ---------------- prep: W2 [64][256] -> uint4-packed bf16 ----------------
// uint4 at (kg*64 + l) holds k = kg*8 .. kg*8+7 for stat l.
// flat bf16 idx = kg*512 + l*8 + q*2 + par  ->  W[l][kg*8 + q*2 + par]
__global__ void prep_w2(const float* __restrict__ W, __hip_bfloat16* __restrict__ dst)
{
    int idx = blockIdx.x * 256 + threadIdx.x;
    if (idx >= 64 * 256) return;
    int par = idx & 1, q = (idx >> 1) & 3, l = (idx >> 3) & 63, kg = idx >> 9;
    dst[idx] = __float2bfloat16(W[l * 256 + kg * 8 + q * 2 + par]);
}

// ---------------- prep: W_ih [768][40] -> uint4-packed [kp][j][gate(+pad)] bf16 ----------------
// uint4 at (kp*256 + j): .x = gate r pair, .y = gate z pair, .z = gate n pair, .w = 0
// flat bf16 idx = kp*2048 + j*8 + g*2 + par -> W[(g*256+j)*40 + kp*2 + par]
__global__ void prep_wih(const float* __restrict__ W, __hip_bfloat16* __restrict__ dst)
{
    int idx = blockIdx.x * 256 + threadIdx.x;
    if (idx >= 20 * 256 * 8) return;
    int par = idx & 1, g = (idx >> 1) & 3, j = (idx >> 3) & 255, kp = idx >> 11;
    float v = 0.f;
    if (g < 3) v = W[(g * 256 + j) * 40 + kp * 2 + par];
    dst[idx] = __float2bfloat16(v);
}

// ---------------- fused obs encoder via MFMA -> Qpre[t][b][:] = emb @ Wq1_e^T + b_q1 (fp32) ----
// Block = 64 rows (of B*T = 131072), 256 threads = 4 waves; wave = one 16-row M-tile.
// 3 layers back-to-back: L1 (K=64, A direct from global fp32->bf16 regs),
// L2/L3 (K=256, A from LDS bf16 activations). B-frags prepacked (prep_bfrag).
// C-layout per 16x16x32: col = lane&15, row = (lane>>4)*4 + reg.
__global__ void __launch_bounds__(256) obs_enc_k(
    const float* __restrict__ obs,
    const bf16x8* __restrict__ Wf1, const float* __restrict__ be1,
    const bf16x8* __restrict__ Wf2, const float* __restrict__ be2,
    const bf16x8* __restrict__ Wf3, const float* __restrict__ bq1,
    float* __restrict__ Qpre)
{
    __shared__ __hip_bfloat16 H1[64][264];
    __shared__ __hip_bfloat16 H2[64][264];
    const int tid = threadIdx.x;
    const int wave = tid >> 6, lane = tid & 63;
    const int am = lane & 15, aq = lane >> 4;
    const int r0 = blockIdx.x * 64;
    const int arow = wave * 16 + am;          // A-operand row within block
    const int orow = wave * 16 + aq * 4;      // C-output row base within block

    // ---- Layer 1: K=64, A loaded straight from global, converted to bf16 ----
    bf16x8 af0, af1;
    {
        float tmp[8];
        const float* src = obs + (size_t)(r0 + arow) * 64 + aq * 8;
        *(float4*)&tmp[0] = *(const float4*)&src[0];
        *(float4*)&tmp[4] = *(const float4*)&src[4];
        af0 = pack8(tmp);
        *(float4*)&tmp[0] = *(const float4*)&src[32];
        *(float4*)&tmp[4] = *(const float4*)&src[36];
        af1 = pack8(tmp);
    }
    {
        const bf16x8* w1 = Wf1 + lane;
#pragma unroll 2
        for (int nt = 0; nt < 16; ++nt) {
            f32x4 acc = {0.f, 0.f, 0.f, 0.f};
            acc = __builtin_amdgcn_mfma_f32_16x16x32_bf16(af0, w1[(size_t)(nt * 2 + 0) * 64], acc, 0, 0, 0);
            acc = __builtin_amdgcn_mfma_f32_16x16x32_bf16(af1, w1[(size_t)(nt * 2 + 1) * 64], acc, 0, 0, 0);
            const int col = nt * 16 + am;
            float b = be1[col];
#pragma unroll
            for (int reg = 0; reg < 4; ++reg)
                H1[orow + reg][col] = __float2bfloat16(eluf(acc[reg] + b));
        }
    }
    __syncthreads();

    // ---- Layer 2: K=256, A from H1 ----
    {
        bf16x8 af[8];
#pragma unroll
        for (int ks = 0; ks < 8; ++ks)
            af[ks] = *(const bf16x8*)&H1[arow][ks * 32 + aq * 8];
        const bf16x8* w2 = Wf2 + lane;
#pragma unroll 2
        for (int nt = 0; nt < 16; ++nt) {
            f32x4 acc = {0.f, 0.f, 0.f, 0.f};
#pragma unroll
            for (int ks = 0; ks < 8; ++ks)
                acc = __builtin_amdgcn_mfma_f32_16x16x32_bf16(af[ks], w2[(size_t)(nt * 8 + ks) * 64], acc, 0, 0, 0);
            const int col = nt * 16 + am;
            float b = be2[col];
#pragma unroll
            for (int reg = 0; reg < 4; ++reg)
                H2[orow + reg][col] = __float2bfloat16(eluf(acc[reg] + b));
        }
    }
    __syncthreads();

    // ---- Layer 3: K=256, A from H2, epilogue -> Qpre (fp32, + b_q1) ----
    {
        bf16x8 af[8];
#pragma unroll
        for (int ks = 0; ks < 8; ++ks)
            af[ks] = *(const bf16x8*)&H2[arow][ks * 32 + aq * 8];
        const bf16x8* w3 = Wf3 + lane;
#pragma unroll 2
        for (int nt = 0; nt < 16; ++nt) {
            f32x4 acc = {0.f, 0.f, 0.f, 0.f};
#pragma unroll
            for (int ks = 0; ks < 8; ++ks)
                acc = __builtin_amdgcn_mfma_f32_16x16x32_bf16(af[ks], w3[(size_t)(nt * 8 + ks) * 64], acc, 0, 0, 0);
            const int col = nt * 16 + am;
            float b = bq1[col];
#pragma unroll
            for (int reg = 0; reg < 4; ++reg) {
                const int r = r0 + orow + reg;
                const int bb = r >> 7, tt = r & (TT - 1);   // row = b*T + t
                Qpre[((size_t)tt * BB + bb) * HHID + col] = acc[reg] + b;
            }
        }
    }
}

// ---------------- main sequential kernel: block = RR=4 batch rows, 512 threads (8 waves) ----------------
// Round-4 WINNER, byte-identical. Per-wave Phase A: 10 CONTIGUOUS tiles, bbuf[2][8]
// register double-buffer, unroll 2. 512 threads @ launch_bounds(512,2) -> 100 VGPR,
// no spill (1024-thread blocks get a 64-VGPR budget on this toolchain -> spill ->
// L2 thrash; measured rounds 1 & 5).
__global__ void __launch_bounds__(512, 2) rssm_seq(
    const float* __restrict__ act, const float* __restrict__ noise,
    const __hip_bfloat16* __restrict__ Wfrag, const float* __restrict__ b_p1,
    const float* __restrict__ b_hh, const float* __restrict__ Qpre,
    const uint4* __restrict__ Wp2q, const float* __restrict__ b_p2,
    const uint4* __restrict__ Wq2q, const float* __restrict__ b_q2,
    const uint4* __restrict__ Wihq, const float* __restrict__ b_ih,
    float* __restrict__ out)
{
    __shared__ float CA[RR][NC];                // P1 | Q1 | gh for our RR rows
    __shared__ float h32[RR][DD];
    __shared__ __hip_bfloat16 hbf[16][264];     // MFMA A operand, rows RR..15 zero, +8 pad
    __shared__ float zl[RR][SS];
    __shared__ float actl[RR][8];
    __shared__ float qbuf[2][RR][HHID];         // Qpre staging, double-buffered by t

    const int tid = threadIdx.x;
    const int wave = tid >> 6, lane = tid & 63;
    const int blk = blockIdx.x;

    for (int i = tid; i < 16 * 264; i += 512) ((unsigned short*)hbf)[i] = 0;
    for (int i = tid; i < RR * DD; i += 512) ((float*)h32)[i] = 0.f;
    {   // prologue: stage Qpre for t = 0
        const int qi = tid * 2, qreg = qi >> 8, qcol = qi & 255;
        *(float2*)&qbuf[0][qreg][qcol] =
            *(const float2*)&Qpre[((size_t)0 * BB + blk * RR + qreg) * HHID + qcol];
    }
    __syncthreads();

    const int am = lane & 15, aq = lane >> 4;
    // wave handles CONTIGUOUS N-tiles nt = wave*10 + i, i = 0..9
    const bf16x8* wp = (const bf16x8*)Wfrag + (size_t)wave * 80 * 64 + lane;

    for (int t = 0; t < TT; ++t) {
        // ---- early prefetches (register consumers far downstream) ----
        if (tid < RR * 8) {
            int row = tid >> 3, c = tid & 7;
            actl[row][c] = act[((size_t)(blk * RR + row) * TT + t) * 8 + c];
        }
        float nval = 0.f;
        if (wave >= 4 && lane < 32)
            nval = noise[((size_t)t * BB + blk * RR + (wave & 3)) * SS + lane];
        float2 qv = make_float2(0.f, 0.f);
        if (t + 1 < TT) {
            const int qi = tid * 2, qreg = qi >> 8, qcol = qi & 255;
            qv = *(const float2*)&Qpre[((size_t)(t + 1) * BB + blk * RR + qreg) * HHID + qcol];
        }

        // ======== Phase A: CA[RR][1280] = epilogue(h @ Wcomb^T) via MFMA ========
        bf16x8 afr[8];
#pragma unroll
        for (int ks = 0; ks < 8; ++ks)
            afr[ks] = *(const bf16x8*)&hbf[am][ks * 32 + aq * 8];

        bf16x8 bbuf[2][8];
#pragma unroll
        for (int ks = 0; ks < 8; ++ks) bbuf[0][ks] = wp[(size_t)ks * 64];
#pragma unroll 2
        for (int i = 0; i < 10; ++i) {
            const int cb = i & 1;
            if (i < 9) {
#pragma unroll
                for (int ks = 0; ks < 8; ++ks)
                    bbuf[cb ^ 1][ks] = wp[(size_t)((i + 1) * 8 + ks) * 64];
            }
            f32x4 acc = {0.f, 0.f, 0.f, 0.f};
#pragma unroll
            for (int ks = 0; ks < 8; ++ks)
                acc = __builtin_amdgcn_mfma_f32_16x16x32_bf16(afr[ks], bbuf[cb][ks], acc, 0, 0, 0);
            const int nt = wave * 10 + i;
            if (lane < 16) {   // quad 0 holds rows 0..3 (row = reg, col = nt*16+lane)
                const int col = nt * 16 + lane;
                if (nt < 16) {
#pragma unroll
                    for (int reg = 0; reg < RR; ++reg)
                        CA[reg][col] = eluf(acc[reg] + b_p1[col]);
                } else if (nt < 32) {
#pragma unroll
                    for (int reg = 0; reg < RR; ++reg)
                        CA[reg][col] = eluf(acc[reg] + qbuf[t & 1][reg][col - 256]);
                } else {
#pragma unroll
                    for (int reg = 0; reg < RR; ++reg)
                        CA[reg][col] = acc[reg] + b_hh[col - 512];
                }
            }
        }
        bar_lds();

        // ======== Phase B1: stats + z. 8 waves: wave = (isq<<2) | row ========
        {
            const int row = wave & 3, isq = wave >> 2;
            const float* car = CA[row] + (isq ? 256 : 0);
            const uint4* W2 = isq ? Wq2q : Wp2q;
            float dA = isq ? b_q2[lane] : b_p2[lane];
            float dB = 0.f;
#pragma unroll 4
            for (int kg = 0; kg < 32; ++kg) {
                uint4 wv = W2[kg * 64 + lane];
                float4 c0 = *(const float4*)&car[kg * 8];
                float4 c1 = *(const float4*)&car[kg * 8 + 4];
                float2 w;
                w = bf2f2(wv.x); dA += c0.x * w.x + c0.y * w.y;
                w = bf2f2(wv.y); dB += c0.z * w.x + c0.w * w.y;
                w = bf2f2(wv.z); dA += c1.x * w.x + c1.y * w.y;
                w = bf2f2(wv.w); dB += c1.z * w.x + c1.w * w.y;
            }
            float d = dA + dB;
            const int r = blk * RR + row;
            float* orow = out + ((size_t)r * TT + t) * 416;
            float v = (lane < 32) ? d : __expf(clip75(d));
            if (!isq) {
                orow[288 + lane] = v;                        // prior mean | prior std
            } else {
                orow[352 + lane] = v;                        // post mean | post std
                float qs_hi = __shfl(v, lane + 32, 64);
                if (lane < 32) {
                    float z = v + qs_hi * nval;
                    zl[row][lane] = z;
                    orow[256 + lane] = z;
                }
            }
        }
        // stage Qpre for t+1 (loads issued at step top, hidden under the B1 dot)
        if (t + 1 < TT) {
            const int qi = tid * 2;
            *(float2*)&qbuf[(t + 1) & 1][qi >> 8][qi & 255] = qv;
        }
        bar_lds();

        // ======== Phase B2: GRU. thread = (rh = tid>>8, column j = tid&255), 2 rows/thread ====
        {
            const int j = tid & 255, rh = tid >> 8;
            float g0[2], g1[2], g2[2];
            float br = b_ih[j], bz = b_ih[256 + j], bn = b_ih[512 + j];
#pragma unroll
            for (int rr = 0; rr < 2; ++rr) { g0[rr] = br; g1[rr] = bz; g2[rr] = bn; }
#pragma unroll 4
            for (int kp = 0; kp < 20; ++kp) {
                uint4 w4 = Wihq[kp * 256 + j];
                float2 wr = bf2f2(w4.x), wz = bf2f2(w4.y), wn = bf2f2(w4.z);
#pragma unroll
                for (int rr = 0; rr < 2; ++rr) {
                    const int r = rh * 2 + rr;
                    float2 a2 = (kp < 16) ? *(const float2*)&zl[r][kp * 2]
                                          : *(const float2*)&actl[r][(kp - 16) * 2];
                    g0[rr] += a2.x * wr.x + a2.y * wr.y;
                    g1[rr] += a2.x * wz.x + a2.y * wz.y;
                    g2[rr] += a2.x * wn.x + a2.y * wn.y;
                }
            }
#pragma unroll
            for (int rr = 0; rr < 2; ++rr) {
                const int r = rh * 2 + rr;
                float rg = sigf(g0[rr] + CA[r][512 + j]);
                float ug = sigf(g1[rr] + CA[r][768 + j]);
                float ng = tanhf_(g2[rr] + rg * CA[r][1024 + j]);
                float hold = h32[r][j];
                float hn = (1.f - ug) * ng + ug * hold;
                out[((size_t)(blk * RR + r) * TT + t) * 416 + j] = hold;  // h at step entry
                h32[r][j] = hn;
                hbf[r][j] = __float2bfloat16(hn);
            }
        }
        bar_lds();   // hbf/h32/CA/qbuf stable before next step's Phase A
    }
}

extern "C" void kernel_launch(void* const* d_in, const int* in_sizes, int n_in,
                              void* d_out, int out_size, void* d_ws, size_t ws_size,
                              hipStream_t stream)
{
    const float* obs   = (const float*)d_in[0];
    const float* act   = (const float*)d_in[1];
    const float* noise = (const float*)d_in[2];
    const float* W_e1  = (const float*)d_in[3];
    const float* b_e1  = (const float*)d_in[4];
    const float* W_e2  = (const float*)d_in[5];
    const float* b_e2  = (const float*)d_in[6];
    const float* W_ih  = (const float*)d_in[7];
    const float* W_hh  = (const float*)d_in[8];
    const float* b_ih  = (const float*)d_in[9];
    const float* b_hh  = (const float*)d_in[10];
    const float* W_p1  = (const float*)d_in[11];
    const float* b_p1  = (const float*)d_in[12];
    const float* W_p2  = (const float*)d_in[13];
    const float* b_p2  = (const float*)d_in[14];
    const float* W_q1  = (const float*)d_in[15];
    const float* b_q1  = (const float*)d_in[16];
    const float* W_q2  = (const float*)d_in[17];
    const float* b_q2  = (const float*)d_in[18];
    float* outp = (float*)d_out;

    // workspace layout
    const size_t qpre_elems = (size_t)TT * BB * HHID;           // 33,554,432 f32
    float* Qpre  = (float*)d_ws;
    __hip_bfloat16* Wfrag = (__hip_bfloat16*)(Qpre + qpre_elems);  // 1280*256
    __hip_bfloat16* Wp2b  = Wfrag + NC * DD;                       // 16384 (uint4-packed)
    __hip_bfloat16* Wq2b  = Wp2b + 64 * 256;                       // 16384 (uint4-packed)
    __hip_bfloat16* Wihb  = Wq2b + 64 * 256;                       // 40960 (uint4-packed, padded)
    __hip_bfloat16* We1f  = Wihb + 20 * 256 * 8;                   // 256*64  (B-frag)
    __hip_bfloat16* We2f  = We1f + 256 * 64;                       // 256*256 (B-frag)
    __hip_bfloat16* Wq1f  = We2f + 256 * 256;                      // 256*256 (B-frag, emb part)
    size_t total_bytes = (char*)(Wq1f + 256 * 256) - (char*)d_ws;
    if (ws_size < total_bytes) return;

    prep_wcomb<<<(NC * DD + 255) / 256, 256, 0, stream>>>(W_p1, W_q1, W_hh, Wfrag);
    prep_w2<<<(64 * 256 + 255) / 256, 256, 0, stream>>>(W_p2, Wp2b);
    prep_w2<<<(64 * 256 + 255) / 256, 256, 0, stream>>>(W_q2, Wq2b);
    prep_wih<<<(20 * 256 * 8 + 255) / 256, 256, 0, stream>>>(W_ih, Wihb);
    prep_bfrag<<<(256 * 64 + 255) / 256, 256, 0, stream>>>(W_e1, We1f, 256, 64, 0, 64);
    prep_bfrag<<<(256 * 256 + 255) / 256, 256, 0, stream>>>(W_e2, We2f, 256, 256, 0, 256);
    prep_bfrag<<<(256 * 256 + 255) / 256, 256, 0, stream>>>(W_q1, Wq1f, 256, 256, 256, 512);

    obs_enc_k<<<dim3((BB * TT) / 64), dim3(256), 0, stream>>>(
        obs, (const bf16x8*)We1f, b_e1, (const bf16x8*)We2f, b_e2,
        (const bf16x8*)Wq1f, b_q1, Qpre);

    rssm_seq<<<dim3(BB / RR), dim3(512), 0, stream>>>(
        act, noise, Wfrag, b_p1, b_hh, Qpre,
        (const uint4*)Wp2b, b_p2,
        (const uint4*)Wq2b, b_q2,
        (const uint4*)Wihb, b_ih, outp);
}